// Round 9
// baseline (198.176 us; speedup 1.0000x reference)
//
#include <hip/hip_runtime.h>

#define N_SEL 8192
#define SUB_SZ 32
#define N_SUB 256
#define N_GRAPH 64
#define N_FULL 12288
#define E_RAW 262144
#define N_PERS 4
#define D 128
#define EPSILON 0.1f
#define LAMB1 0.5f

#define CAP_E 96                  // raw-edge bin capacity per row (lambda~21)
#define OVF_CAP 8192              // overflow list (expected use: 0)
#define LPR (N_FULL / 16)         // 768 cache lines (64 B) per row
#define BM_WORDS (N_FULL * LPR / 32)   // 294,912 words = 1.2 MB line bitmap

typedef float f4_t __attribute__((ext_vector_type(4)));

// ---- workspace layout ----
#define OFF_COUNTS   0
#define OFF_INVMAP   ((size_t)N_FULL * 4)
#define OFF_ATTR     (OFF_INVMAP + (size_t)N_FULL * 4)
#define OFF_RAWCOLS  (OFF_ATTR + (size_t)N_SEL * SUB_SZ * 4)
#define OFF_OVFCNT   (OFF_RAWCOLS + (size_t)N_FULL * CAP_E * 4)
#define OFF_OVF      (OFF_OVFCNT + 16)
#define OFF_BITMAP   (OFF_OVF + (size_t)OVF_CAP * 8)
#define WS_NEEDED    (OFF_BITMAP + (size_t)BM_WORDS * 4)

__global__ __launch_bounds__(256) void prep_kernel(int* __restrict__ counts,
                                                   int* __restrict__ inv_map,
                                                   int* __restrict__ ovf_cnt,
                                                   unsigned* __restrict__ bitmap)
{
    int t = blockIdx.x * 256 + threadIdx.x;
    if (t < BM_WORDS) bitmap[t] = 0u;
    if (t < N_FULL) { counts[t] = 0; inv_map[t] = -1; }
    if (t == 0) *ovf_cnt = 0;
}

// Blocks [0,256): subgraph cosine blocks -> compact attr values + inv_map
//                 + mark touched 64B lines in bitmap.
// Blocks [256,1280): raw edges -> per-row bins + mark lines.
__global__ __launch_bounds__(256) void build_kernel(
        const float* __restrict__ x,
        const float* __restrict__ Wc,
        const float* __restrict__ sscore,
        const int*   __restrict__ smap,
        const int*   __restrict__ rei,
        int*   __restrict__ counts,
        int*   __restrict__ inv_map,
        float* __restrict__ attr_vals,
        int*   __restrict__ raw_cols,
        int*   __restrict__ ovf_cnt,
        uint2* __restrict__ ovf,
        unsigned* __restrict__ bitmap)
{
    const int tid = threadIdx.x;

    if (blockIdx.x >= N_SUB) {
        int e = (blockIdx.x - N_SUB) * 256 + tid;
        int r = rei[e];
        int c = rei[E_RAW + e];
        int slot = atomicAdd(&counts[r], 1);
        if (slot < CAP_E) {
            raw_cols[(size_t)r * CAP_E + slot] = c;
            int line = r * LPR + (c >> 4);
            atomicOr(&bitmap[line >> 5], 1u << (line & 31));
        } else {
            int o = atomicAdd(ovf_cnt, 1);
            if (o < OVF_CAP) ovf[o] = make_uint2((unsigned)r, (unsigned)c);
        }
        return;
    }

    const int s    = blockIdx.x;
    const int base = s * SUB_SZ;

    __shared__ float xs[SUB_SZ][D + 1];
    __shared__ float w2[N_PERS][D];
    __shared__ float rnorm[N_PERS][SUB_SZ];
    __shared__ int   map_s[SUB_SZ];
    __shared__ float rowscore;

    for (int k = tid; k < SUB_SZ * D; k += 256) {
        int i = k >> 7;
        int d = k & (D - 1);
        xs[i][d] = x[(base + i) * D + d];
    }
    for (int k = tid; k < N_PERS * D; k += 256) {
        float w = Wc[k];
        ((float*)w2)[k] = w * w;
    }
    if (tid < SUB_SZ) {
        int m = smap[base + tid];
        map_s[tid] = m;
        inv_map[m] = base + tid;
    }
    if (tid == 0) {
        int g4 = (s >> 2) << 2;
        float sum = sscore[g4] + sscore[g4 + 1] + sscore[g4 + 2] + sscore[g4 + 3];
        rowscore = (sscore[s] / sum) * LAMB1;
    }
    __syncthreads();

    if (tid < N_PERS * SUB_SZ) {
        int p = tid >> 5;
        int i = tid & 31;
        float acc = 0.f;
        #pragma unroll 8
        for (int d = 0; d < D; ++d) {
            float v = xs[i][d];
            acc = fmaf(v * v, w2[p][d], acc);
        }
        rnorm[p][i] = 1.0f / fmaxf(sqrtf(acc), 1e-12f);
    }
    __syncthreads();

    for (int e = tid; e < SUB_SZ * SUB_SZ; e += 256) {
        int i = e >> 5;
        int j = e & 31;
        float v = 0.f;
        if (i != j) {
            float a0 = 0.f, a1 = 0.f, a2 = 0.f, a3 = 0.f;
            #pragma unroll 8
            for (int d = 0; d < D; ++d) {
                float prod = xs[i][d] * xs[j][d];
                a0 = fmaf(prod, w2[0][d], a0);
                a1 = fmaf(prod, w2[1][d], a1);
                a2 = fmaf(prod, w2[2][d], a2);
                a3 = fmaf(prod, w2[3][d], a3);
            }
            float adj = 0.25f * (a0 * rnorm[0][i] * rnorm[0][j] +
                                 a1 * rnorm[1][i] * rnorm[1][j] +
                                 a2 * rnorm[2][i] * rnorm[2][j] +
                                 a3 * rnorm[3][i] * rnorm[3][j]);
            if (adj > EPSILON) {
                v = adj * rowscore;
                int line = map_s[i] * LPR + (map_s[j] >> 4);
                atomicOr(&bitmap[line >> 5], 1u << (line & 31));
            }
        }
        attr_vals[(size_t)base * SUB_SZ + e] = v;
    }
}

// ---- fused fill + patch, ONE launch, disjoint 64B lines ----
// Blocks [0, N_FULL): patch -- compose each marked line of row r exactly
//   (dedupe + duplicate-sum over the row's <=128 entries) and write it as a
//   full 64B NT store (write-only, no RMW).
// Blocks [N_FULL, N_FULL+FILL_BLOCKS): fill -- contiguous NT zero stream
//   (R3 pattern), skipping marked lines via bitmap test (L2-resident).
#define FILL_BLOCKS 4096
#define N4_TOTAL 37748736
#define PER_BLOCK (N4_TOTAL / FILL_BLOCKS)   // 9216 float4 per block
#define FILL_ITERS (PER_BLOCK / 256)         // 36

__global__ __launch_bounds__(256) void fillpatch_kernel(
        const int*   __restrict__ counts,
        const int*   __restrict__ inv_map,
        const float* __restrict__ attr_vals,
        const int*   __restrict__ raw_cols,
        const int*   __restrict__ smap,
        const unsigned* __restrict__ bitmap,
        float* __restrict__ out)
{
    const int tid = threadIdx.x;

    if (blockIdx.x >= N_FULL) {
        // ---------------- fill part ----------------
        const int b = blockIdx.x - N_FULL;
        const size_t base4 = (size_t)b * PER_BLOCK + tid;
        const f4_t z = (f4_t){0.f, 0.f, 0.f, 0.f};
        f4_t* out4 = (f4_t*)out;
        #pragma unroll
        for (int k = 0; k < FILL_ITERS; ++k) {
            size_t idx4 = base4 + (size_t)k * 256;
            unsigned line = (unsigned)(idx4 >> 2);
            unsigned w = bitmap[line >> 5];
            if (!((w >> (line & 31u)) & 1u))
                __builtin_nontemporal_store(z, &out4[idx4]);
        }
        return;
    }

    // ---------------- patch part: one block per output row ----------------
    const int r = blockIdx.x;
    __shared__ uint2 ents[CAP_E + SUB_SZ];
    __shared__ int nloc;

    int cnt = counts[r];
    if (cnt > CAP_E) cnt = CAP_E;
    if (tid == 0) nloc = cnt;
    __syncthreads();

    if (tid < cnt)
        ents[tid] = make_uint2((unsigned)raw_cols[(size_t)r * CAP_E + tid],
                               __float_as_uint(1.0f - LAMB1));
    int i = inv_map[r];
    if (i >= 0 && tid < SUB_SZ) {
        float v = attr_vals[(size_t)i * SUB_SZ + tid];
        if (v != 0.f) {
            int c = smap[(i >> 5) * SUB_SZ + tid];
            int s = atomicAdd(&nloc, 1);
            ents[s] = make_uint2((unsigned)c, __float_as_uint(v));
        }
    }
    __syncthreads();

    const int n = nloc;
    for (int e = tid; e < n; e += 256) {
        unsigned line = ents[e].x >> 4;
        bool leader = true;
        for (int e2 = 0; e2 < e; ++e2)
            if ((ents[e2].x >> 4) == line) { leader = false; break; }
        if (!leader) continue;

        float vals[16];
        #pragma unroll
        for (int q = 0; q < 16; ++q) vals[q] = 0.f;
        for (int e2 = e; e2 < n; ++e2) {
            uint2 q2 = ents[e2];
            if ((q2.x >> 4) == line) {
                float qv = __uint_as_float(q2.y);
                int sl = (int)(q2.x & 15u);
                #pragma unroll
                for (int q = 0; q < 16; ++q)
                    vals[q] += (q == sl) ? qv : 0.f;   // static reg index
            }
        }
        f4_t* lp = (f4_t*)(out + (size_t)r * N_FULL + ((size_t)line << 4));
        #pragma unroll
        for (int q = 0; q < 4; ++q)
            __builtin_nontemporal_store(((f4_t*)vals)[q], &lp[q]);
    }
}

__global__ __launch_bounds__(256) void ovf_kernel(const int* __restrict__ ovf_cnt,
                                                  const uint2* __restrict__ ovf,
                                                  float* __restrict__ out)
{
    int n = *ovf_cnt;
    if (n > OVF_CAP) n = OVF_CAP;
    for (int t = blockIdx.x * 256 + threadIdx.x; t < n; t += gridDim.x * 256) {
        uint2 e = ovf[t];
        atomicAdd(&out[(size_t)e.x * N_FULL + e.y], 1.0f - LAMB1);
    }
}

// ---------------- fallback path (R3): zero fill + atomic scatter ----------------
__global__ __launch_bounds__(256) void zero_kernel(f4_t* __restrict__ out)
{
    size_t base = (size_t)blockIdx.x * PER_BLOCK + threadIdx.x;
    const f4_t z = (f4_t){0.f, 0.f, 0.f, 0.f};
    #pragma unroll
    for (int k = 0; k < FILL_ITERS; ++k)
        __builtin_nontemporal_store(z, &out[base + (size_t)k * 256]);
}

__global__ __launch_bounds__(256) void scatter_kernel(
        const float* __restrict__ x,
        const float* __restrict__ Wc,
        const float* __restrict__ sscore,
        const int*   __restrict__ smap,
        const int*   __restrict__ rei,
        float* __restrict__ out)
{
    const int tid = threadIdx.x;

    if (blockIdx.x >= N_SUB) {
        int e = (blockIdx.x - N_SUB) * 256 + tid;
        long long r = rei[e];
        long long c = rei[E_RAW + e];
        atomicAdd(&out[r * (long long)N_FULL + c], 1.0f - LAMB1);
        return;
    }

    const int s    = blockIdx.x;
    const int base = s * SUB_SZ;

    __shared__ float xs[SUB_SZ][D + 1];
    __shared__ float w2[N_PERS][D];
    __shared__ float rnorm[N_PERS][SUB_SZ];
    __shared__ int   map_s[SUB_SZ];
    __shared__ float rowscore;

    for (int k = tid; k < SUB_SZ * D; k += 256) {
        int i = k >> 7;
        int d = k & (D - 1);
        xs[i][d] = x[(base + i) * D + d];
    }
    for (int k = tid; k < N_PERS * D; k += 256) {
        float w = Wc[k];
        ((float*)w2)[k] = w * w;
    }
    if (tid < SUB_SZ) map_s[tid] = smap[base + tid];
    if (tid == 0) {
        int g4 = (s >> 2) << 2;
        float sum = sscore[g4] + sscore[g4 + 1] + sscore[g4 + 2] + sscore[g4 + 3];
        rowscore = (sscore[s] / sum) * LAMB1;
    }
    __syncthreads();

    if (tid < N_PERS * SUB_SZ) {
        int p = tid >> 5;
        int i = tid & 31;
        float acc = 0.f;
        #pragma unroll 8
        for (int d = 0; d < D; ++d) {
            float v = xs[i][d];
            acc = fmaf(v * v, w2[p][d], acc);
        }
        rnorm[p][i] = 1.0f / fmaxf(sqrtf(acc), 1e-12f);
    }
    __syncthreads();

    for (int e = tid; e < SUB_SZ * SUB_SZ; e += 256) {
        int i = e >> 5;
        int j = e & 31;
        if (i == j) continue;
        float a0 = 0.f, a1 = 0.f, a2 = 0.f, a3 = 0.f;
        #pragma unroll 8
        for (int d = 0; d < D; ++d) {
            float prod = xs[i][d] * xs[j][d];
            a0 = fmaf(prod, w2[0][d], a0);
            a1 = fmaf(prod, w2[1][d], a1);
            a2 = fmaf(prod, w2[2][d], a2);
            a3 = fmaf(prod, w2[3][d], a3);
        }
        float adj = 0.25f * (a0 * rnorm[0][i] * rnorm[0][j] +
                             a1 * rnorm[1][i] * rnorm[1][j] +
                             a2 * rnorm[2][i] * rnorm[2][j] +
                             a3 * rnorm[3][i] * rnorm[3][j]);
        if (adj > EPSILON) {
            long long row = map_s[i];
            long long col = map_s[j];
            atomicAdd(&out[row * (long long)N_FULL + col], adj * rowscore);
        }
    }
}

extern "C" void kernel_launch(void* const* d_in, const int* in_sizes, int n_in,
                              void* d_out, int out_size, void* d_ws, size_t ws_size,
                              hipStream_t stream) {
    const float* x      = (const float*)d_in[0];
    const float* Wc     = (const float*)d_in[1];
    const float* sscore = (const float*)d_in[2];
    const int* smap = (const int*)d_in[4];
    const int* rei  = (const int*)d_in[7];
    float* out = (float*)d_out;

    if (ws_size >= WS_NEEDED) {
        char* ws = (char*)d_ws;
        int*      counts    = (int*)(ws + OFF_COUNTS);
        int*      inv_map   = (int*)(ws + OFF_INVMAP);
        float*    attr_vals = (float*)(ws + OFF_ATTR);
        int*      raw_cols  = (int*)(ws + OFF_RAWCOLS);
        int*      ovf_cnt   = (int*)(ws + OFF_OVFCNT);
        uint2*    ovf       = (uint2*)(ws + OFF_OVF);
        unsigned* bitmap    = (unsigned*)(ws + OFF_BITMAP);

        prep_kernel<<<BM_WORDS / 256, 256, 0, stream>>>(counts, inv_map, ovf_cnt, bitmap);
        build_kernel<<<N_SUB + E_RAW / 256, 256, 0, stream>>>(
            x, Wc, sscore, smap, rei, counts, inv_map, attr_vals, raw_cols,
            ovf_cnt, ovf, bitmap);
        fillpatch_kernel<<<N_FULL + FILL_BLOCKS, 256, 0, stream>>>(
            counts, inv_map, attr_vals, raw_cols, smap, bitmap, out);
        ovf_kernel<<<16, 256, 0, stream>>>(ovf_cnt, ovf, out);
    } else {
        zero_kernel<<<FILL_BLOCKS, 256, 0, stream>>>((f4_t*)out);
        scatter_kernel<<<N_SUB + E_RAW / 256, 256, 0, stream>>>(
            x, Wc, sscore, smap, rei, out);
    }
}